// Round 5
// baseline (3319.479 us; speedup 1.0000x reference)
//
#include <hip/hip_runtime.h>
#include <math.h>

#define HID 51
#define NROW 204  // 4*HID, torch gate order [i|f|g|o]
#define TMAIN 1024
#define FUT 64
#define TT (TMAIN + FUT)

__device__ __forceinline__ float fast_sigmoid(float x) {
  return 1.0f / (1.0f + __expf(-x));
}
__device__ __forceinline__ float fast_tanh(float x) {
  return 1.0f - 2.0f / (__expf(2.0f * x) + 1.0f);
}

// Opaque def: result of asm cannot be rematerialized from the global load.
#define PIN4(v) asm("" : "+v"((v).x), "+v"((v).y), "+v"((v).z), "+v"((v).w))

// Load float4 #q of a 51-float row; q is a literal so the tail guards fold.
__device__ __forceinline__ float4 load_q(const float* row, int q) {
  float4 v;
  v.x = (4 * q + 0 < HID) ? row[4 * q + 0] : 0.0f;
  v.y = (4 * q + 1 < HID) ? row[4 * q + 1] : 0.0f;
  v.z = (4 * q + 2 < HID) ? row[4 * q + 2] : 0.0f;
  v.w = (4 * q + 3 < HID) ? row[4 * q + 3] : 0.0f;
  return v;
}

#define QLIST(F) F(0) F(1) F(2) F(3) F(4) F(5) F(6) F(7) F(8) F(9) F(10) F(11) F(12)

#define DECL_LOAD(q)                          \
  float4 wa##q = load_q(rowA, q); PIN4(wa##q); \
  float4 wb##q = load_q(rowB, q); PIN4(wb##q); \
  float4 wc##q = load_q(rowC, q); PIN4(wc##q);

// S1: two independent dots (8 accumulators of ILP): Wh1[t].h1  and  Wh2[t].h2
#define S1_Q(q) {                              \
    float4 hv1 = h1v[q];                       \
    float4 hv2 = h2v[q];                       \
    acc1.x = fmaf(hv1.x, wa##q.x, acc1.x);     \
    acc1.y = fmaf(hv1.y, wa##q.y, acc1.y);     \
    acc1.z = fmaf(hv1.z, wa##q.z, acc1.z);     \
    acc1.w = fmaf(hv1.w, wa##q.w, acc1.w);     \
    acc2.x = fmaf(hv2.x, wb##q.x, acc2.x);     \
    acc2.y = fmaf(hv2.y, wb##q.y, acc2.y);     \
    acc2.z = fmaf(hv2.z, wb##q.z, acc2.z);     \
    acc2.w = fmaf(hv2.w, wb##q.w, acc2.w); }

// S3: Wi2[t].h1_new
#define S3_Q(q) {                              \
    float4 hv = h1v[q];                        \
    acc3.x = fmaf(hv.x, wc##q.x, acc3.x);      \
    acc3.y = fmaf(hv.y, wc##q.y, acc3.y);      \
    acc3.z = fmaf(hv.z, wc##q.z, acc3.z);      \
    acc3.w = fmaf(hv.w, wc##q.w, acc3.w); }

// One block = one batch element; thread t<204 owns gate-row t of Wh1/Wh2/Wi2
// (156 named weight floats). R4 post-mortem: launch_bounds(256,2) only sets
// waves-per-eu MIN=2 (a VGPR cap), so the scheduler still targeted 4 waves/EU
// (VGPR_Count=128) and spilled all weights to scratch (WRITE_SIZE 17MB).
// amdgpu_waves_per_eu(2,2) also caps the MAX -> occupancy target 2 waves/EU,
// RA budget 256 VGPR, weights must stay resident. 8 waves/CU, 2 blocks/CU,
// all 512 blocks co-resident.
__attribute__((amdgpu_waves_per_eu(2, 2)))
__global__ __launch_bounds__(256)
void lstm2_persistent(const float* __restrict__ input,
                      const float* __restrict__ Wi1,
                      const float* __restrict__ Wh1,
                      const float* __restrict__ bi1,
                      const float* __restrict__ bh1,
                      const float* __restrict__ Wi2,
                      const float* __restrict__ Wh2,
                      const float* __restrict__ bi2,
                      const float* __restrict__ bh2,
                      const float* __restrict__ Wlin,
                      const float* __restrict__ blin,
                      float* __restrict__ out) {
  __shared__ __align__(16) float lds_x[TMAIN];
  __shared__ __align__(16) float lds_h1[64];  // slots 51..63 stay 0 (pad)
  __shared__ __align__(16) float lds_h2[64];
  __shared__ __align__(16) float lds_a1[NROW];
  __shared__ __align__(16) float lds_a2[NROW];
  __shared__ float lds_fb;

  const int b = blockIdx.x;
  const int t = threadIdx.x;
  const bool rowact = t < NROW;
  const int r = rowact ? t : 0;  // clamped row index for idle lanes

  for (int i = t; i < TMAIN; i += 256) lds_x[i] = input[b * TMAIN + i];
  if (t < 64) {
    lds_h1[t] = 0.0f;
    lds_h2[t] = 0.0f;
  }

  const float* rowA = Wh1 + r * HID;
  const float* rowB = Wh2 + r * HID;
  const float* rowC = Wi2 + r * HID;
  QLIST(DECL_LOAD)

  const float b1s = bi1[r] + bh1[r];
  const float b2s = bi2[r] + bh2[r];
  const float wi1r = Wi1[r];
  const float wlin_t = (t < HID) ? Wlin[t] : 0.0f;
  const float blin_s = blin[0];
  float c1 = 0.0f, c2 = 0.0f;
  float p2 = 0.0f;

  __syncthreads();

  const float4* h1v = (const float4*)lds_h1;
  const float4* h2v = (const float4*)lds_h2;

  for (int step = 0; step < TT; ++step) {
    // ---- S1: a1[t] = Wh1[t].h1 + x*Wi1[t] + b1 ; p2 = Wh2[t].h2 (in reg) ----
    {
      float x = (step < TMAIN) ? lds_x[step] : lds_fb;
      float4 acc1 = {0.f, 0.f, 0.f, 0.f};
      float4 acc2 = {0.f, 0.f, 0.f, 0.f};
      QLIST(S1_Q)
      float a1 = (acc1.x + acc1.y) + (acc1.z + acc1.w) + fmaf(x, wi1r, b1s);
      p2 = (acc2.x + acc2.y) + (acc2.z + acc2.w);
      if (rowact) lds_a1[t] = a1;
    }
    __syncthreads();

    // ---- S2: layer-1 cell update (c1 in regs of threads 0..50) ----
    if (t < HID) {
      float gi = fast_sigmoid(lds_a1[t]);
      float gf = fast_sigmoid(lds_a1[HID + t]);
      float gg = fast_tanh(lds_a1[2 * HID + t]);
      float go = fast_sigmoid(lds_a1[3 * HID + t]);
      c1 = gf * c1 + gi * gg;
      lds_h1[t] = go * fast_tanh(c1);
    }
    __syncthreads();

    // ---- S3: a2[t] = Wi2[t].h1_new + p2 + b2 ----
    {
      float4 acc3 = {0.f, 0.f, 0.f, 0.f};
      QLIST(S3_Q)
      float a2 = (acc3.x + acc3.y) + (acc3.z + acc3.w) + p2 + b2s;
      if (rowact) lds_a2[t] = a2;
    }
    __syncthreads();

    // ---- S4: layer-2 cell + linear head (wave 0) ----
    if (t < 64) {
      float val = 0.0f;
      if (t < HID) {
        float gi = fast_sigmoid(lds_a2[t]);
        float gf = fast_sigmoid(lds_a2[HID + t]);
        float gg = fast_tanh(lds_a2[2 * HID + t]);
        float go = fast_sigmoid(lds_a2[3 * HID + t]);
        c2 = gf * c2 + gi * gg;
        float h2n = go * fast_tanh(c2);
        lds_h2[t] = h2n;
        val = wlin_t * h2n;
      }
#pragma unroll
      for (int off = 32; off >= 1; off >>= 1) val += __shfl_xor(val, off);
      if (t == 0) {
        float o = val + blin_s;
        out[b * TT + step] = o;
        lds_fb = o;  // feedback input for the future phase
      }
    }
    __syncthreads();  // h2_new + fb visible for next step's S1
  }
}

extern "C" void kernel_launch(void* const* d_in, const int* in_sizes, int n_in,
                              void* d_out, int out_size, void* d_ws,
                              size_t ws_size, hipStream_t stream) {
  const float* input = (const float*)d_in[0];
  const float* Wi1 = (const float*)d_in[1];
  const float* Wh1 = (const float*)d_in[2];
  const float* bi1 = (const float*)d_in[3];
  const float* bh1 = (const float*)d_in[4];
  const float* Wi2 = (const float*)d_in[5];
  const float* Wh2 = (const float*)d_in[6];
  const float* bi2 = (const float*)d_in[7];
  const float* bh2 = (const float*)d_in[8];
  const float* Wlin = (const float*)d_in[9];
  const float* blin = (const float*)d_in[10];
  float* out = (float*)d_out;

  const int B = in_sizes[0] / TMAIN;  // 512
  lstm2_persistent<<<B, 256, 0, stream>>>(input, Wi1, Wh1, bi1, bh1, Wi2, Wh2,
                                          bi2, bh2, Wlin, blin, out);
}

// Round 6
// 3165.220 us; speedup vs baseline: 1.0487x; 1.0487x over previous
//
#include <hip/hip_runtime.h>
#include <math.h>

#define HID 51
#define NROW 204  // 4*HID, torch gate order [i|f|g|o]
#define TMAIN 1024
#define FUT 64
#define TT (TMAIN + FUT)

__device__ __forceinline__ float fast_sigmoid(float x) {
  return 1.0f / (1.0f + __expf(-x));
}
__device__ __forceinline__ float fast_tanh(float x) {
  return 1.0f - 2.0f / (__expf(2.0f * x) + 1.0f);
}

// Opaque def: result cannot be rematerialized from the global load.
#define PIN4(v) asm("" : "+v"((v).x), "+v"((v).y), "+v"((v).z), "+v"((v).w))

// Load float4 #q of a 51-float row; q literal so tail guards fold. k=51 pads 0.
__device__ __forceinline__ float4 load_q(const float* row, int q) {
  float4 v;
  v.x = (4 * q + 0 < HID) ? row[4 * q + 0] : 0.0f;
  v.y = (4 * q + 1 < HID) ? row[4 * q + 1] : 0.0f;
  v.z = (4 * q + 2 < HID) ? row[4 * q + 2] : 0.0f;
  v.w = (4 * q + 3 < HID) ? row[4 * q + 3] : 0.0f;
  return v;
}

#define QLIST(F) F(0) F(1) F(2) F(3) F(4) F(5) F(6) F(7) F(8) F(9) F(10) F(11) F(12)

// ONE row of ONE matrix per thread: 13 named float4 = 52 weight floats.
// R1-R5 post-mortem: the allocator hard-caps this kernel at 128 VGPRs (spilled
// 156-float/thread layouts to scratch across 5 variants, WRITE_SIZE up to
// 54 MB). 52 floats + overhead ~80 VGPR fits UNDER the cap -> no spill, no
// allocator fight.
#define DECL_W(q) float4 w##q = load_q(rowW, q); PIN4(w##q);

// acc += w[.] . hv4[.]  (52 floats; h slots 51..63 are zero-padded)
#define DOT_Q(q) {                          \
    float4 hv = hv4[q];                     \
    acc.x = fmaf(hv.x, w##q.x, acc.x);      \
    acc.y = fmaf(hv.y, w##q.y, acc.y);      \
    acc.z = fmaf(hv.z, w##q.z, acc.z);      \
    acc.w = fmaf(hv.w, w##q.w, acc.w); }

// One block = one batch element, 768 threads (12 waves):
//   g0 (t 0..255):   row u of Wh1; S1: a1 = Wh1.h1 + x*Wi1 + b1 -> lds_a1
//   g1 (t 256..511): row u of Wh2; S1: p2 = Wh2.h2 -> lds_p2
//   g2 (t 512..767): row u of Wi2; S3: a2 = Wi2.h1new + p2 + b2 -> lds_a2
// S2: layer-1 cell (threads 0..50, c1 in regs). S4: layer-2 cell + linear
// head (wave 0, c2 in regs, shuffle reduce). 4 barriers/step.
__global__ __launch_bounds__(768)
void lstm2_persistent(const float* __restrict__ input,
                      const float* __restrict__ Wi1,
                      const float* __restrict__ Wh1,
                      const float* __restrict__ bi1,
                      const float* __restrict__ bh1,
                      const float* __restrict__ Wi2,
                      const float* __restrict__ Wh2,
                      const float* __restrict__ bi2,
                      const float* __restrict__ bh2,
                      const float* __restrict__ Wlin,
                      const float* __restrict__ blin,
                      float* __restrict__ out) {
  __shared__ __align__(16) float lds_x[TMAIN];
  __shared__ __align__(16) float lds_h1[64];  // slots 51..63 stay 0 (pad)
  __shared__ __align__(16) float lds_h2[64];
  __shared__ __align__(16) float lds_a1[NROW];
  __shared__ __align__(16) float lds_a2[NROW];
  __shared__ __align__(16) float lds_p2[NROW];
  __shared__ float lds_fb;

  const int b = blockIdx.x;
  const int tid = threadIdx.x;
  const int g = tid >> 8;   // matrix group: 0=Wh1, 1=Wh2, 2=Wi2
  const int u = tid & 255;  // row slot within group
  const bool rowact = u < NROW;
  const int r = rowact ? u : 0;  // clamped row index for idle lanes

  for (int i = tid; i < TMAIN; i += 768) lds_x[i] = input[b * TMAIN + i];
  if (tid < 64) {
    lds_h1[tid] = 0.0f;
    lds_h2[tid] = 0.0f;
  }

  const float* rowW = ((g == 0) ? Wh1 : ((g == 1) ? Wh2 : Wi2)) + r * HID;
  QLIST(DECL_W)

  const float b1s = bi1[r] + bh1[r];  // used by g0
  const float b2s = bi2[r] + bh2[r];  // used by g2
  const float wi1r = Wi1[r];          // used by g0
  const float wlin_t = (tid < HID) ? Wlin[tid] : 0.0f;  // wave 0
  const float blin_s = blin[0];
  float c1 = 0.0f, c2 = 0.0f;

  __syncthreads();

  const float4* h1v = (const float4*)lds_h1;
  const float4* h2v = (const float4*)lds_h2;

  for (int step = 0; step < TT; ++step) {
    // ---- S1: g0: a1 = Wh1.h1 + x*Wi1 + b1 ; g1: p2 = Wh2.h2 ----
    if (g == 0) {
      float x = (step < TMAIN) ? lds_x[step] : lds_fb;
      float4 acc = {0.f, 0.f, 0.f, 0.f};
      const float4* hv4 = h1v;
      QLIST(DOT_Q)
      float a1 = (acc.x + acc.y) + (acc.z + acc.w) + fmaf(x, wi1r, b1s);
      if (rowact) lds_a1[u] = a1;
    } else if (g == 1) {
      float4 acc = {0.f, 0.f, 0.f, 0.f};
      const float4* hv4 = h2v;
      QLIST(DOT_Q)
      if (rowact) lds_p2[u] = (acc.x + acc.y) + (acc.z + acc.w);
    }
    __syncthreads();

    // ---- S2: layer-1 cell (threads 0..50, c1 in regs) ----
    if (tid < HID) {
      float gi = fast_sigmoid(lds_a1[tid]);
      float gf = fast_sigmoid(lds_a1[HID + tid]);
      float gg = fast_tanh(lds_a1[2 * HID + tid]);
      float go = fast_sigmoid(lds_a1[3 * HID + tid]);
      c1 = gf * c1 + gi * gg;
      lds_h1[tid] = go * fast_tanh(c1);
    }
    __syncthreads();

    // ---- S3: g2: a2 = Wi2.h1_new + p2 + b2 ----
    if (g == 2) {
      float4 acc = {0.f, 0.f, 0.f, 0.f};
      const float4* hv4 = h1v;
      QLIST(DOT_Q)
      float a2 = (acc.x + acc.y) + (acc.z + acc.w) + lds_p2[r] + b2s;
      if (rowact) lds_a2[u] = a2;
    }
    __syncthreads();

    // ---- S4: layer-2 cell + linear head (wave 0, c2 in regs) ----
    if (tid < 64) {
      float val = 0.0f;
      if (tid < HID) {
        float gi = fast_sigmoid(lds_a2[tid]);
        float gf = fast_sigmoid(lds_a2[HID + tid]);
        float gg = fast_tanh(lds_a2[2 * HID + tid]);
        float go = fast_sigmoid(lds_a2[3 * HID + tid]);
        c2 = gf * c2 + gi * gg;
        float h2n = go * fast_tanh(c2);
        lds_h2[tid] = h2n;
        val = wlin_t * h2n;
      }
#pragma unroll
      for (int off = 32; off >= 1; off >>= 1) val += __shfl_xor(val, off);
      if (tid == 0) {
        float o = val + blin_s;
        out[b * TT + step] = o;
        lds_fb = o;  // feedback input for the future phase
      }
    }
    __syncthreads();  // h2_new + fb visible for next step's S1
  }
}

extern "C" void kernel_launch(void* const* d_in, const int* in_sizes, int n_in,
                              void* d_out, int out_size, void* d_ws,
                              size_t ws_size, hipStream_t stream) {
  const float* input = (const float*)d_in[0];
  const float* Wi1 = (const float*)d_in[1];
  const float* Wh1 = (const float*)d_in[2];
  const float* bi1 = (const float*)d_in[3];
  const float* bh1 = (const float*)d_in[4];
  const float* Wi2 = (const float*)d_in[5];
  const float* Wh2 = (const float*)d_in[6];
  const float* bi2 = (const float*)d_in[7];
  const float* bh2 = (const float*)d_in[8];
  const float* Wlin = (const float*)d_in[9];
  const float* blin = (const float*)d_in[10];
  float* out = (float*)d_out;

  const int B = in_sizes[0] / TMAIN;  // 512
  lstm2_persistent<<<B, 768, 0, stream>>>(input, Wi1, Wh1, bi1, bh1, Wi2, Wh2,
                                          bi2, bh2, Wlin, blin, out);
}